// Round 14
// baseline (609.660 us; speedup 1.0000x reference)
//
#include <hip/hip_runtime.h>

#define BB 2
#define NN 4096
#define CC 256
#define FF 1024
#define NLAYER 4
#define RR (BB*NN)
#define QKLD (3*CC)      // qkv packed row stride = 768
#define NEG_BIG (-1e30f)
#define LOG2E 1.44269504f

typedef _Float16 h16;
typedef __attribute__((ext_vector_type(8))) _Float16 half8;
typedef __attribute__((ext_vector_type(4))) float f32x4;

#define WAITVM(n) asm volatile("s_waitcnt vmcnt(" #n ")" ::: "memory")

// ---------------- async global->LDS, 16B per lane ----------------
__device__ __forceinline__ void gload16(const h16* g, h16* l) {
    __builtin_amdgcn_global_load_lds((const __attribute__((address_space(1))) void*)g,
                                     (__attribute__((address_space(3))) void*)l, 16, 0, 0);
}

// stage ROWS x 64 h16 chunk into lds[ROWS][64] with piece-XOR swizzle
template<int ROWS, int THREADS>
__device__ __forceinline__ void stage_rows(const h16* __restrict__ src, int ld,
    int row0, int c0, h16* lds, int tid)
{
    int w = tid >> 6;
    #pragma unroll
    for (int t = 0; t < (ROWS*8)/THREADS; ++t) {
        int slot = t*THREADS + tid;
        int row = slot >> 3;
        int pp  = slot & 7;
        int piece = pp ^ (row & 7);
        gload16(src + (size_t)(row0 + row)*ld + c0 + piece*8,
                lds + (t*THREADS + w*64)*8);    // wave-uniform base; HW adds lane*16B
    }
}

// read 8 contiguous h16 (logical k-piece pl) of LDS row
__device__ __forceinline__ half8 frag_ld(const h16* lds, int row, int pl) {
    return *(const half8*)(lds + row*64 + ((pl ^ (row & 7))*8));
}

// ---------------- weight transpose+convert: W[K,N] f32 -> WT[N,K] f16 ----------------
__global__ __launch_bounds__(256) void pct_wtrans(const float* __restrict__ W,
    h16* __restrict__ WT, int K, int N, int dstride, float scale)
{
    __shared__ h16 t[32][33];
    const float* Wl = W + (size_t)blockIdx.z*K*N;
    h16* WTl = WT + (size_t)blockIdx.z*dstride;
    int k0 = blockIdx.x*32, n0 = blockIdx.y*32;
    int tx = threadIdx.x & 31, ty = threadIdx.x >> 5;
    #pragma unroll
    for (int i = ty; i < 32; i += 8)
        t[i][tx] = (h16)(Wl[(size_t)(k0+i)*N + n0 + tx] * scale);
    __syncthreads();
    #pragma unroll
    for (int i = ty; i < 32; i += 8)
        WTl[(size_t)(n0+i)*K + k0 + tx] = t[tx][i];
}

// combined q/k/v transpose into packed [NLAYER][768][256]; q scaled by log2(e).
// Corner blocks (x==0,y==0) also pack the q/k/v biases into bqkv[NLAYER][768].
__global__ __launch_bounds__(256) void pct_wtrans_qkv(const float* __restrict__ wq,
    const float* __restrict__ wk, const float* __restrict__ wv,
    const float* __restrict__ bq, const float* __restrict__ bk, const float* __restrict__ bv,
    h16* __restrict__ WT, float* __restrict__ bqkv)
{
    __shared__ h16 t[32][33];
    int z = blockIdx.z;
    int which = z >> 2, layer = z & 3;          // NLAYER == 4
    const float* Wl = (which == 0 ? wq : which == 1 ? wk : wv) + (size_t)layer*CC*CC;
    h16* WTl = WT + (size_t)layer*QKLD*CC + (size_t)which*CC*CC;
    float scale = (which == 0) ? LOG2E : 1.0f;
    int k0 = blockIdx.x*32, n0 = blockIdx.y*32;
    int tx = threadIdx.x & 31, ty = threadIdx.x >> 5;
    #pragma unroll
    for (int i = ty; i < 32; i += 8)
        t[i][tx] = (h16)(Wl[(size_t)(k0+i)*CC + n0 + tx] * scale);
    if (blockIdx.x == 0 && blockIdx.y == 0) {
        const float* bsrc = (which == 0 ? bq : which == 1 ? bk : bv);
        bqkv[layer*QKLD + which*CC + threadIdx.x] = bsrc[layer*CC + threadIdx.x] * scale;
    }
    __syncthreads();
    #pragma unroll
    for (int i = ty; i < 32; i += 8)
        WTl[(size_t)(n0+i)*CC + k0 + tx] = t[tx][i];
}

// ---------------- fold LN0 into w1: W'_b[n,k] = A_{b,k} w1[k,n]; bias'_b[n] = b1[n] + sum_k B_{b,k} w1[k,n]
__global__ __launch_bounds__(256) void pct_wfold(const float* __restrict__ w1,
    const float* __restrict__ sums, const float* __restrict__ ls, const float* __restrict__ lb,
    const float* __restrict__ b1, h16* __restrict__ w1Tb, float* __restrict__ biasb)
{
    __shared__ h16 t[32][33];
    __shared__ float bb[8][32];
    int b = blockIdx.z;
    int k0 = blockIdx.x*32, n0 = blockIdx.y*32;
    int tx = threadIdx.x & 31, ty = threadIdx.x >> 5;
    float psum = 0.f;
    #pragma unroll
    for (int i = ty; i < 32; i += 8) {
        int k = k0 + i;
        float s1 = sums[(b*CC + k)*2], s2 = sums[(b*CC + k)*2 + 1];
        float mu  = s1 * (1.f/NN);
        float var = s2 * (1.f/NN) - mu*mu;
        float rstd = rsqrtf(var + 1e-6f);
        float A = rstd * ls[k];
        float Bv = lb[k] - mu * rstd * ls[k];
        float wv = w1[(size_t)k*CC + n0 + tx];
        t[i][tx] = (h16)(wv * A);
        psum += Bv * wv;
    }
    bb[ty][tx] = psum;
    __syncthreads();
    if (ty == 0) {
        float s = 0.f;
        #pragma unroll
        for (int r = 0; r < 8; ++r) s += bb[r][tx];
        if (k0 == 0) s += b1[n0 + tx];
        atomicAdd(&biasb[b*CC + n0 + tx], s);
    }
    #pragma unroll
    for (int i = ty; i < 32; i += 8)
        w1Tb[(size_t)b*CC*CC + (size_t)(n0+i)*CC + k0 + tx] = t[tx][i];
}

// ---------------- embed + fused column stats ----------------
__global__ __launch_bounds__(256) void pct_embed(const float* __restrict__ inp,
    const float* __restrict__ w0, const float* __restrict__ b0,
    h16* __restrict__ out, float* __restrict__ sums)
{
    int c = threadIdx.x;
    int r0 = blockIdx.x * 64;
    float wa = w0[c], wb = w0[CC+c], wcv = w0[2*CC+c], bb = b0[c];
    float s1 = 0.f, s2 = 0.f;
    #pragma unroll 4
    for (int i = 0; i < 64; ++i) {
        int r = r0 + i;
        float y = bb + inp[r*3+0]*wa + inp[r*3+1]*wb + inp[r*3+2]*wcv;
        h16 hy = (h16)y;
        out[(size_t)r*CC + c] = hy;
        float yf = (float)hy;
        s1 += yf; s2 += yf*yf;
    }
    int b = r0 >> 12;
    atomicAdd(&sums[((size_t)b*CC + c)*2 + 0], s1);
    atomicAdd(&sums[((size_t)b*CC + c)*2 + 1], s2);
}

// ---------------- apply LN (stats over points), optional relu + residual ----------------
__global__ __launch_bounds__(256) void pct_lnapply(const h16* __restrict__ x, int ldx,
    const float* __restrict__ sums, const float* __restrict__ scale, const float* __restrict__ bias,
    const h16* __restrict__ res, int ldr, h16* __restrict__ out, int ldo,
    int do_relu)
{
    int r = blockIdx.x*8 + (threadIdx.x >> 5);
    int cg = (threadIdx.x & 31) * 8;
    int b = r / NN;
    half8 xv = *(const half8*)(x + (size_t)r*ldx + cg);
    half8 rv;
    if (res) rv = *(const half8*)(res + (size_t)r*ldr + cg);
    half8 ov;
    #pragma unroll
    for (int j = 0; j < 8; ++j) {
        int c = cg + j;
        float s1 = sums[(b*CC + c)*2], s2 = sums[(b*CC + c)*2 + 1];
        float mu  = s1 * (1.f/NN);
        float var = s2 * (1.f/NN) - mu*mu;
        float rstd = rsqrtf(var + 1e-6f);
        float y = ((float)xv[j] - mu) * rstd * scale[c] + bias[c];
        if (do_relu) y = fmaxf(y, 0.f);
        if (res) y += (float)rv[j];
        ov[j] = (h16)y;
    }
    *(half8*)(out + (size_t)r*ldo + cg) = ov;
}

// ---------------- f16 MFMA GEMM (NT); per-batch weight/bias strides wbs/bbs ----------------
template<int BN, bool OUT_F32, bool CSTAT>
__global__ __launch_bounds__(256) void pct_gemm_f16(
    const h16* __restrict__ A, int lda,
    const h16* __restrict__ WT, const float* __restrict__ bias,
    void* __restrict__ outp, int ldo, int K, const float* __restrict__ rowS,
    float* __restrict__ csums, int wbs, int bbs)
{
    constexpr int BJ = BN/2;
    constexpr int NF = BJ/16;
    __shared__ __align__(16) h16 Asm[128*64];
    __shared__ __align__(16) h16 Bsm[BN*64];
    const int tid = threadIdx.x;
    const int lane = tid & 63, w = tid >> 6;
    const int ln = lane & 15, lq = lane >> 4;
    const int wr = w >> 1, wc = w & 1;
    const int m0 = blockIdx.x*128, n0 = blockIdx.y*BN;
    WT   += (size_t)(m0 >> 12) * wbs;
    bias += (size_t)(m0 >> 12) * bbs;
    f32x4 acc[4][NF];
    #pragma unroll
    for (int i = 0; i < 4; ++i)
        #pragma unroll
        for (int j = 0; j < NF; ++j) acc[i][j] = (f32x4){0.f,0.f,0.f,0.f};
    for (int k0 = 0; k0 < K; k0 += 64) {
        stage_rows<128,256>(A, lda, m0, k0, Asm, tid);
        stage_rows<BN,256>(WT, K, n0, k0, Bsm, tid);
        __syncthreads();
        #pragma unroll
        for (int kk = 0; kk < 2; ++kk) {
            half8 af[4], bfr[NF];
            #pragma unroll
            for (int i = 0; i < 4; ++i) af[i] = frag_ld(Asm, wr*64 + i*16 + ln, kk*4 + lq);
            #pragma unroll
            for (int j = 0; j < NF; ++j) bfr[j] = frag_ld(Bsm, wc*BJ + j*16 + ln, kk*4 + lq);
            #pragma unroll
            for (int i = 0; i < 4; ++i)
                #pragma unroll
                for (int j = 0; j < NF; ++j)
                    acc[i][j] = __builtin_amdgcn_mfma_f32_16x16x32_f16(af[i], bfr[j], acc[i][j], 0, 0, 0);
        }
        __syncthreads();
    }
    float cs1[NF], cs2[NF];
    #pragma unroll
    for (int j = 0; j < NF; ++j) {
        int col = n0 + wc*BJ + j*16 + ln;
        float bv = bias[col];
        float s1 = 0.f, s2 = 0.f;
        #pragma unroll
        for (int i = 0; i < 4; ++i) {
            #pragma unroll
            for (int r = 0; r < 4; ++r) {
                int row = m0 + wr*64 + i*16 + lq*4 + r;
                float sc = 1.f;
                if (rowS) { float s = rowS[row]; sc = s / (1e-9f + s); }
                float v = acc[i][j][r] * sc + bv;
                if (OUT_F32) ((float*)outp)[(size_t)row*ldo + col] = v;
                else ((h16*)outp)[(size_t)row*ldo + col] = (h16)v;
                if (CSTAT) { s1 += v; s2 += v*v; }
            }
        }
        cs1[j] = s1; cs2[j] = s2;
    }
    if constexpr (CSTAT) {
        __shared__ float cred[2][2][BJ][2];
        #pragma unroll
        for (int j = 0; j < NF; ++j) {
            float s1 = cs1[j], s2 = cs2[j];
            s1 += __shfl_down(s1, 16); s1 += __shfl_down(s1, 32);
            s2 += __shfl_down(s2, 16); s2 += __shfl_down(s2, 32);
            if (lane < 16) {
                cred[wr][wc][j*16 + lane][0] = s1;
                cred[wr][wc][j*16 + lane][1] = s2;
            }
        }
        __syncthreads();
        if (tid < 2*BN) {
            int c = tid >> 1, st = tid & 1;
            int wcc = c >> 5, ci = c & 31;
            float v = cred[0][wcc][ci][st] + cred[1][wcc][ci][st];
            int b = m0 >> 12;
            atomicAdd(&csums[((size_t)b*CC + n0 + c)*2 + st], v);
        }
    }
}

// ---------------- pass A: row max/sumexp2 of (log2e-scaled) Q@K^T ----------------
// m201 geometry: 8 waves (2m x 4n), 256x256 S-tile, both operands streamed via
// double-buffered 32KB chunks (128KB LDS, 1 block/CU). 4 BK-steps of 64; per step
// per wave: 24 ds_read -> 64 MFMA between one barrier-pair; counted vmcnt(8).
// Full-K accumulation -> exact per-wave row stats, no online merging.
// Partials: part[(b*NN+m)*64 + nt*4 + wn] (16 n-tiles x 4 n-waves).
__global__ __launch_bounds__(512, 2) void attn_rowstats(const h16* __restrict__ QKV,
    float2* __restrict__ part)
{
    __shared__ __align__(16) h16 SM[2][2][256*64];   // [buf][0=Q,1=K], 128 KB
    const int b = blockIdx.x, mt = blockIdx.y, nt = blockIdx.z;
    const int tid = threadIdx.x;
    const int lane = tid & 63, w = tid >> 6;
    const int ln = lane & 15, lq = lane >> 4;
    const int wm = w >> 2, wn = w & 3;               // 2 m-halves x 4 n-slices
    const h16* qb = QKV + (size_t)b*NN*QKLD;
    const h16* kb = qb + CC;
    const int m0 = mt*256, n0 = nt*256;

    f32x4 acc[8][4];
    #pragma unroll
    for (int mi = 0; mi < 8; ++mi)
        #pragma unroll
        for (int ni = 0; ni < 4; ++ni) acc[mi][ni] = (f32x4){0.f,0.f,0.f,0.f};

    stage_rows<256,512>(qb, QKLD, m0, 0, SM[0][0], tid);
    stage_rows<256,512>(kb, QKLD, n0, 0, SM[0][1], tid);
    for (int s = 0; s < 4; ++s) {
        if (s + 1 < 4) {
            stage_rows<256,512>(qb, QKLD, m0, (s+1)*64, SM[(s+1)&1][0], tid);
            stage_rows<256,512>(kb, QKLD, n0, (s+1)*64, SM[(s+1)&1][1], tid);
            WAITVM(8);        // FIFO [step s:8][step s+1:8] -> step s landed
        } else {
            WAITVM(0);
        }
        __builtin_amdgcn_s_barrier();
        const h16* bufA = SM[s&1][0];
        const h16* bufB = SM[s&1][1];
        __builtin_amdgcn_s_setprio(1);
        #pragma unroll
        for (int kk = 0; kk < 2; ++kk) {
            half8 af[8], bf[4];
            #pragma unroll
            for (int mi = 0; mi < 8; ++mi)
                af[mi] = frag_ld(bufA, wm*128 + mi*16 + ln, kk*4 + lq);
            #pragma unroll
            for (int ni = 0; ni < 4; ++ni)
                bf[ni] = frag_ld(bufB, wn*64 + ni*16 + ln, kk*4 + lq);
            #pragma unroll
            for (int mi = 0; mi < 8; ++mi)
                #pragma unroll
                for (int ni = 0; ni < 4; ++ni)
                    acc[mi][ni] = __builtin_amdgcn_mfma_f32_16x16x32_f16(
                        af[mi], bf[ni], acc[mi][ni], 0, 0, 0);
        }
        __builtin_amdgcn_s_setprio(0);
        __builtin_amdgcn_s_barrier();    // reads retired -> next stage may overwrite
    }
    // epilogue: per-row (128 rows of this wave) max/sumexp2 over the wave's 64 cols
    #pragma unroll
    for (int mi = 0; mi < 8; ++mi) {
        #pragma unroll
        for (int r = 0; r < 4; ++r) {
            float lm = fmaxf(fmaxf(acc[mi][0][r], acc[mi][1][r]),
                             fmaxf(acc[mi][2][r], acc[mi][3][r]));
            lm = fmaxf(lm, __shfl_xor(lm, 1, 64));
            lm = fmaxf(lm, __shfl_xor(lm, 2, 64));
            lm = fmaxf(lm, __shfl_xor(lm, 4, 64));
            lm = fmaxf(lm, __shfl_xor(lm, 8, 64));
            float lsv = exp2f(acc[mi][0][r] - lm) + exp2f(acc[mi][1][r] - lm)
                      + exp2f(acc[mi][2][r] - lm) + exp2f(acc[mi][3][r] - lm);
            lsv += __shfl_xor(lsv, 1, 64);
            lsv += __shfl_xor(lsv, 2, 64);
            lsv += __shfl_xor(lsv, 4, 64);
            lsv += __shfl_xor(lsv, 8, 64);
            if (ln == mi) {                 // 4 writer lanes (lq=0..3), rows lq*4+r
                int m = m0 + wm*128 + mi*16 + lq*4 + r;
                part[((size_t)b*NN + m)*64 + nt*4 + wn] = make_float2(lm, lsv);
            }
        }
    }
}

// ---------------- pass B: column sums of softmax (rowcomb inlined; d-fold tail) ----------------
__global__ __launch_bounds__(512, 2) void attn_colsums(const h16* __restrict__ QKV,
    const float2* __restrict__ part, float* __restrict__ S)
{
    __shared__ __align__(16) h16 SM[2][2][256*64];   // 128 KB
    __shared__ float rst_d[256];
    const int b = blockIdx.x, mt = blockIdx.y, nt = blockIdx.z;
    const int tid = threadIdx.x;
    const int lane = tid & 63, w = tid >> 6;
    const int ln = lane & 15, lq = lane >> 4;
    const int wm = w >> 2, wn = w & 3;
    const h16* qb = QKV + (size_t)b*NN*QKLD;
    const h16* kb = qb + CC;
    const int m0 = mt*256, n0 = nt*256;

    // issue step-0 staging first; its latency hides under the rowcomb
    stage_rows<256,512>(qb, QKLD, m0, 0, SM[0][0], tid);
    stage_rows<256,512>(kb, QKLD, n0, 0, SM[0][1], tid);

    // inline rowcomb: combine 64 partials for this block's 256 m-rows -> d[m] in LDS
    if (tid < 256) {
        const float4* pp4 = (const float4*)(part + ((size_t)b*NN + m0 + tid)*64);
        float m = NEG_BIG;
        #pragma unroll 8
        for (int i = 0; i < 32; ++i) {
            float4 v = pp4[i];
            m = fmaxf(m, fmaxf(v.x, v.z));
        }
        float sum = 0.f;
        #pragma unroll 8
        for (int i = 0; i < 32; ++i) {
            float4 v = pp4[i];
            sum += v.y * exp2f(v.x - m) + v.w * exp2f(v.z - m);
        }
        rst_d[tid] = -m - __log2f(sum);
    }
    __syncthreads();   // drains step-0 staging too (it overlapped the rowcomb)

    f32x4 acc[8][4];
    #pragma unroll
    for (int mi = 0; mi < 8; ++mi)
        #pragma unroll
        for (int ni = 0; ni < 4; ++ni) acc[mi][ni] = (f32x4){0.f,0.f,0.f,0.f};

    for (int s = 0; s < 4; ++s) {
        if (s + 1 < 4) {
            stage_rows<256,512>(qb, QKLD, m0, (s+1)*64, SM[(s+1)&1][0], tid);
            stage_rows<256,512>(kb, QKLD, n0, (s+1)*64, SM[(s+1)&1][1], tid);
            WAITVM(8);
        } else {
            WAITVM(0);
        }
        __builtin_amdgcn_s_barrier();
        const h16* bufA = SM[s&1][0];
        const h16* bufB = SM[s&1][1];
        __builtin_amdgcn_s_setprio(1);
        #pragma unroll
        for (int kk = 0; kk < 2; ++kk) {
            half8 af[8], bf[4];
            #pragma unroll
            for (int mi = 0; mi < 8; ++mi)
                af[mi] = frag_ld(bufA, wm*128 + mi*16 + ln, kk*4 + lq);
            #pragma unroll
            for (int ni = 0; ni < 4; ++ni)
                bf[ni] = frag_ld(bufB, wn*64 + ni*16 + ln, kk*4 + lq);
            #pragma unroll
            for (int mi = 0; mi < 8; ++mi)
                #pragma unroll
                for (int ni = 0; ni < 4; ++ni)
                    acc[mi][ni] = __builtin_amdgcn_mfma_f32_16x16x32_f16(
                        af[mi], bf[ni], acc[mi][ni], 0, 0, 0);
        }
        __builtin_amdgcn_s_setprio(0);
        __builtin_amdgcn_s_barrier();
    }
    // epilogue: cs[n] = sum over the wave's 128 m-rows of exp2(acc + d[m])
    float cs[4] = {0.f, 0.f, 0.f, 0.f};
    #pragma unroll
    for (int mi = 0; mi < 8; ++mi) {
        #pragma unroll
        for (int r = 0; r < 4; ++r) {
            float dv = rst_d[wm*128 + mi*16 + lq*4 + r];
            #pragma unroll
            for (int ni = 0; ni < 4; ++ni)
                cs[ni] += exp2f(acc[mi][ni][r] + dv);
        }
    }
    #pragma unroll
    for (int ni = 0; ni < 4; ++ni) {
        cs[ni] += __shfl_xor(cs[ni], 16, 64);
        cs[ni] += __shfl_xor(cs[ni], 32, 64);
    }
    if (lq == 0) {
        #pragma unroll
        for (int ni = 0; ni < 4; ++ni) {
            int n = n0 + wn*64 + ni*16 + ln;
            atomicAdd(&S[(size_t)b*NN + n], cs[ni]);
        }
    }
}

extern "C" void kernel_launch(void* const* d_in, const int* in_sizes, int n_in,
                              void* d_out, int out_size, void* d_ws, size_t ws_size,
                              hipStream_t stream)
{
    const float* inp  = (const float*)d_in[0];
    const float* w0   = (const float*)d_in[1];
    const float* b0   = (const float*)d_in[2];
    const float* ln0s = (const float*)d_in[3];
    const float* ln0b = (const float*)d_in[4];
    const float* w1   = (const float*)d_in[5];
    const float* b1   = (const float*)d_in[6];
    const float* ln1s = (const float*)d_in[7];
    const float* ln1b = (const float*)d_in[8];
    const float* wq   = (const float*)d_in[9];
    const float* bq   = (const float*)d_in[10];
    const float* wk   = (const float*)d_in[11];
    const float* bk   = (const float*)d_in[12];
    const float* wv   = (const float*)d_in[13];
    const float* bv   = (const float*)d_in[14];
    const float* wo   = (const float*)d_in[15];
    const float* bo   = (const float*)d_in[16];
    const float* alns = (const float*)d_in[17];
    const float* alnb = (const float*)d_in[18];
    const float* wf   = (const float*)d_in[19];
    const float* bfb  = (const float*)d_in[20];
    float* out = (float*)d_out;

    // workspace layout
    char* p = (char*)d_ws;
    auto alloc = [&](size_t bytes) { char* r = p; p += (bytes + 255) & ~255ULL; return r; };
    h16* t0    = (h16*)alloc((size_t)RR*CC*2);
    h16* t2    = (h16*)alloc((size_t)RR*CC*2);
    h16* x1    = (h16*)alloc((size_t)RR*CC*2);
    h16* qkv   = (h16*)alloc((size_t)RR*QKLD*2);
    h16* oh    = (h16*)alloc((size_t)RR*CC*2);
    h16* xcat  = (h16*)alloc((size_t)RR*FF*2);
    h16* w1Tb  = (h16*)alloc((size_t)BB*CC*CC*2);   // per-batch LN0-folded w1
    h16* wqkvT = (h16*)alloc((size_t)NLAYER*QKLD*CC*2);
    h16* woT   = (h16*)alloc((size_t)NLAYER*CC*CC*2);
    h16* wfT   = (h16*)alloc((size_t)FF*FF*2);
    float* bqkv  = (float*)alloc((size_t)NLAYER*QKLD*4);
    float2* part  = (float2*)alloc((size_t)RR*64*8);     // 64 partials/row, 4 MB
    float* Ssum  = (float*)alloc((size_t)NLAYER*RR*4);   // zeroed below
    float* lns   = (float*)alloc((size_t)6*BB*CC*2*4);   // zeroed below (adjacent)
    float* biasb = (float*)alloc((size_t)BB*CC*4);       // zeroed below (adjacent)

    dim3 blk(256);

    // zero Ssum..biasb span in one memset (adjacent in layout)
    hipMemsetAsync(Ssum, 0, (size_t)((char*)(biasb + BB*CC) - (char*)Ssum), stream);

    // weight transpose+convert (+pack q/k/v with biases; q scaled by log2e)
    pct_wtrans_qkv<<<dim3(CC/32, CC/32, 3*NLAYER), blk, 0, stream>>>(
        wq, wk, wv, bq, bk, bv, wqkvT, bqkv);
    pct_wtrans<<<dim3(CC/32, CC/32, NLAYER), blk, 0, stream>>>(wo, woT, CC, CC, CC*CC, 1.f);
    pct_wtrans<<<dim3(FF/32, FF/32, 1), blk, 0, stream>>>(wf, wfT, FF, FF, FF*FF, 1.f);

    // pre-conv stack: embed (fused column stats) -> fold LN0 into w1 -> w1 GEMM on raw t0
    pct_embed<<<RR/64, blk, 0, stream>>>(inp, w0, b0, t0, lns + 0*BB*CC*2);
    pct_wfold<<<dim3(CC/32, CC/32, BB), blk, 0, stream>>>(
        w1, lns + 0*BB*CC*2, ln0s, ln0b, b1, w1Tb, biasb);
    pct_gemm_f16<64,false,true><<<dim3(RR/128, CC/64), blk, 0, stream>>>(
        t0, CC, w1Tb, biasb, t2, CC, CC, nullptr, lns + 1*BB*CC*2, CC*CC, CC);
    pct_lnapply<<<RR/8, blk, 0, stream>>>(t2, CC, lns + 1*BB*CC*2, ln1s, ln1b, nullptr, 0, x1, CC, 0);

    const h16* xin = x1; int ldx = CC;
    for (int i = 0; i < NLAYER; ++i) {
        // fused q/k/v GEMM -> qkv[RR][768]
        pct_gemm_f16<64,false,false><<<dim3(RR/128, QKLD/64), blk, 0, stream>>>(
            xin, ldx, wqkvT + (size_t)i*QKLD*CC, bqkv + i*QKLD, qkv, QKLD, CC, nullptr, nullptr, 0, 0);

        attn_rowstats<<<dim3(BB, NN/256, NN/256), dim3(512), 0, stream>>>(qkv, part);
        attn_colsums<<<dim3(BB, NN/256, NN/256), dim3(512), 0, stream>>>(qkv, part, Ssum + (size_t)i*RR);

        // wo GEMM on v (rows scaled by col[m] in epilogue) + fused column stats
        pct_gemm_f16<64,false,true><<<dim3(RR/128, CC/64), blk, 0, stream>>>(
            qkv + 2*CC, QKLD, woT + (size_t)i*CC*CC, bo + i*CC, oh, CC, CC,
            Ssum + (size_t)i*RR, lns + (2+i)*BB*CC*2, 0, 0);

        pct_lnapply<<<RR/8, blk, 0, stream>>>(oh, CC, lns + (2+i)*BB*CC*2, alns + i*CC, alnb + i*CC,
                                              xin, ldx, xcat + i*CC, FF, 1);
        xin = xcat + i*CC; ldx = FF;
    }

    pct_gemm_f16<128,true,false><<<dim3(RR/128, FF/128), blk, 0, stream>>>(
        xcat, FF, wfT, bfb, out, FF, FF, nullptr, nullptr, 0, 0);
}